// Round 10
// baseline (82.748 us; speedup 1.0000x reference)
//
#include <hip/hip_runtime.h>
#include <hip/hip_bf16.h>

// Problem constants (reference: K=512, D=128, N=8192)
#define KC 512
#define DD 128
#define NP 8192

// ws layout (bytes):
//   [0,       2KB)     sumc2   (512 f32)
//   [4096,    +1MB)    part2   (8192 pts x 16 chunks u64 packed (sortable(v)<<32)|cent)
//   [1052672, +128KB)  cntpart (64 g x 512 c i32)
//   [1183744, +16MB)   part    (64 g x 512 c x 128 d f32)

// ---------------- prep: sumc2 only (Ck consumed row-major now) ----------------
__global__ __launch_bounds__(256) void kprep(const float* __restrict__ Ck,
                                             float* __restrict__ sumc2) {
    const int k = blockIdx.x * 256 + threadIdx.x;
    const float4* row = (const float4*)(Ck + k * DD);
    float s = 0.f;
    #pragma unroll
    for (int i = 0; i < 32; ++i) {
        const float4 v = row[i];
        s += v.x * v.x + v.y * v.y + v.z * v.z + v.w * v.w;   // same expr as r9 (bit-identical)
    }
    sumc2[k] = s;
}

// ---------------- assign: x in VGPRs, uniform c loads, no LDS ----------------
// 512 blocks x 256 thr: ch = blk>>5 (centroid chunk of 32), pg = blk&31.
// Thread = point p = pg*256+tid. x row: 128 VGPRs (32 float4, static idx).
// Centroid rows are wave-uniform -> scalar/broadcast loads on the SMEM path,
// VALU does the 128-FMA ascending-d chain (identical order to r9: absmax 0.0).
// 2048 waves = 2/SIMD; dependent FMA chain @4cyc x 2 waves -> SIMD saturated.
__global__ __launch_bounds__(256) void kassign2(const float* __restrict__ X,
                                                const float* __restrict__ Ck,
                                                const float* __restrict__ sumc2,
                                                unsigned long long* __restrict__ part2) {
    const int tid = threadIdx.x;
    const int ch  = blockIdx.x >> 5;        // 0..15
    const int pg  = blockIdx.x & 31;        // 0..31
    const int p   = pg * 256 + tid;
    const int cb  = ch * 32;

    float4 xr[32];
    const float4* xp = (const float4*)(X + (size_t)p * DD);
    #pragma unroll
    for (int i = 0; i < 32; ++i) xr[i] = xp[i];

    float bv = 3.4e38f;
    int   bi = 0;
    #pragma unroll 2
    for (int c = 0; c < 32; ++c) {
        const float4* cr = (const float4*)(Ck + (size_t)(cb + c) * DD);
        float acc = 0.f;
        #pragma unroll
        for (int i = 0; i < 32; ++i) {
            const float4 cv = cr[i];
            acc = fmaf(xr[i].x, cv.x, acc);
            acc = fmaf(xr[i].y, cv.y, acc);
            acc = fmaf(xr[i].z, cv.z, acc);
            acc = fmaf(xr[i].w, cv.w, acc);
        }
        const float v = fmaf(-2.f, acc, sumc2[cb + c]);   // monotonic proxy (same as r9)
        if (v < bv) { bv = v; bi = cb + c; }              // strict < ascending = first min
    }
    // monotone float->uint; pack idx low so u64 min == (min v, then min idx)
    unsigned int b = __float_as_uint(bv);
    b = (b & 0x80000000u) ? ~b : (b | 0x80000000u);
    part2[(size_t)p * 16 + ch] = ((unsigned long long)b << 32) | (unsigned int)bi;
}

// ---------------- hist: min-combine chunks + LDS partial sums ----------------
// 256 blocks x 256 thr: g = b>>2 (128-point group), h = (b>>1)&1 (dim half),
// ch = b&1 (cluster half). LDS tile [256 c][64 d] = 64 KB. Fixed work per
// block regardless of skew (r9-proven, exact).
__global__ __launch_bounds__(256) void khist2(const float* __restrict__ X,
                                              const unsigned long long* __restrict__ part2,
                                              float* __restrict__ part,
                                              int* __restrict__ cntpart) {
    __shared__ float lds[256 * 64];   // 64 KB
    __shared__ int sidx[128];
    __shared__ int cnt[256];
    const int b = blockIdx.x;
    const int g = b >> 2, h = (b >> 1) & 1, ch = b & 1;
    const int t = threadIdx.x;
    const int lane = t & 63;
    const int w = t >> 6;

    {
        float4* lz = (float4*)lds;
        const float4 z = make_float4(0.f, 0.f, 0.f, 0.f);
        #pragma unroll
        for (int i = 0; i < 16; ++i) lz[t + 256 * i] = z;
    }
    cnt[t] = 0;
    if (t < 128) {
        const ulonglong2* pp = (const ulonglong2*)(part2 + (size_t)(g * 128 + t) * 16);
        unsigned long long m = ~0ull;
        #pragma unroll
        for (int i = 0; i < 8; ++i) {
            const ulonglong2 v = pp[i];
            m = (v.x < m) ? v.x : m;
            m = (v.y < m) ? v.y : m;
        }
        sidx[t] = (int)(m & 0xffffffffull);
    }
    __syncthreads();

    const int clo = ch * 256;
    if (h == 0 && t < 128) {
        const int cl = sidx[t] - clo;
        if ((unsigned)cl < 256u) atomicAdd(&cnt[cl], 1);
    }

    const float* Xh = X + (size_t)g * 128 * DD + h * 64 + lane;
    #pragma unroll 4
    for (int i = 0; i < 32; ++i) {
        const int p = w * 32 + i;
        const int cl = sidx[p] - clo;            // wave-uniform
        if ((unsigned)cl < 256u) {
            const float x = Xh[p * DD];          // 256B coalesced per wave
            atomicAdd(&lds[cl * 64 + lane], x);  // LDS ds_add_f32
        }
    }
    __syncthreads();

    // writeout 256x64 tile -> part[g][clo+cl][h*64 + d]  (4096 float4, 16/thread)
    const float4* ls = (const float4*)lds;
    float* pg_ = part + (size_t)g * (KC * DD);
    #pragma unroll
    for (int r = 0; r < 16; ++r) {
        const int j  = r * 256 + t;              // 0..4095
        const int cl = j >> 4;
        const int dq = j & 15;
        *(float4*)&pg_[(clo + cl) * DD + h * 64 + dq * 4] = ls[j];
    }
    if (h == 0) cntpart[g * KC + clo + t] = cnt[t];
}

// ---------------- reduce: out[c][:] = sum_g part[g][c][:], + nItems ----------------
// 512 blocks x 128 thr. Fixed ascending-g order (deterministic, exact).
__global__ __launch_bounds__(128) void kreduce2(const float* __restrict__ part,
                                                const int* __restrict__ cntpart,
                                                float* __restrict__ out) {
    const int c = blockIdx.x;
    const int d = threadIdx.x;
    const float* pc = part + (size_t)c * DD + d;
    float s = 0.f;
    #pragma unroll 8
    for (int g = 0; g < 64; ++g) s += pc[(size_t)g * (KC * DD)];
    out[c * DD + d] = s;

    if (d < 64) {
        int v = cntpart[d * KC + c];
        #pragma unroll
        for (int off = 32; off > 0; off >>= 1) v += __shfl_xor(v, off);
        if (d == 0) out[KC * DD + c] = (float)v;
    }
}

extern "C" void kernel_launch(void* const* d_in, const int* in_sizes, int n_in,
                              void* d_out, int out_size, void* d_ws, size_t ws_size,
                              hipStream_t stream) {
    const float* locF = (const float*)d_in[0];
    const float* Ck   = (const float*)d_in[1];
    float* out     = (float*)d_out;
    char*  ws      = (char*)d_ws;
    float* sumc2   = (float*)(ws);
    unsigned long long* part2 = (unsigned long long*)(ws + 4096);
    int*   cntpart = (int*)(ws + 1052672);
    float* part    = (float*)(ws + 1183744);

    hipLaunchKernelGGL(kprep,    dim3(2),   dim3(256), 0, stream, Ck, sumc2);
    hipLaunchKernelGGL(kassign2, dim3(512), dim3(256), 0, stream, locF, Ck, sumc2, part2);
    hipLaunchKernelGGL(khist2,   dim3(256), dim3(256), 0, stream, locF, part2, part, cntpart);
    hipLaunchKernelGGL(kreduce2, dim3(512), dim3(128), 0, stream, part, cntpart, out);
}

// Round 11
// 81.399 us; speedup vs baseline: 1.0166x; 1.0166x over previous
//
#include <hip/hip_runtime.h>
#include <hip/hip_bf16.h>

// Problem constants (reference: K=512, D=128, N=8192)
#define KC 512
#define DD 128
#define NP 8192

// ws layout (bytes):
//   [0,       2KB)     sumc2   (512 f32)
//   [4096,    +1MB)    part2   (8192 pts x 16 chunks u64 packed (sortable(v)<<32)|cent)
//   [1052672, +128KB)  cntpart (64 g x 512 c i32)
//   [1183744, +16MB)   part    (64 g x 512 c x 128 d f32)

// ---------------- prep: sumc2 only ----------------
__global__ __launch_bounds__(256) void kprep(const float* __restrict__ Ck,
                                             float* __restrict__ sumc2) {
    const int k = blockIdx.x * 256 + threadIdx.x;
    const float4* row = (const float4*)(Ck + k * DD);
    float s = 0.f;
    #pragma unroll
    for (int i = 0; i < 32; ++i) {
        const float4 v = row[i];
        s += v.x * v.x + v.y * v.y + v.z * v.z + v.w * v.w;   // same expr as r9/r10 (bit-identical)
    }
    sumc2[k] = s;
}

// ---------------- assign: x resident in VGPRs, 4-way cent chains ----------------
// 512 blocks x 256 thr: ch = blk>>5 (centroid chunk of 32), pg = blk&31.
// Thread = point p. x row: 128 VGPRs -- __launch_bounds__(256,2) raises the VGPR
// cap to ~256 so xr STAYS resident (r10 failure: cap 68 -> x re-read from L2
// every c-iter = 0.5 GB L2 traffic). Centroid rows are wave-uniform scalar/
// broadcast loads; 4 concurrent dot chains give ILP to cover FMA + load latency.
// Per-cent accumulation order identical to r9/r10 (ascending d): absmax 0.0.
__global__ __launch_bounds__(256, 2) void kassign2(const float* __restrict__ X,
                                                   const float* __restrict__ Ck,
                                                   const float* __restrict__ sumc2,
                                                   unsigned long long* __restrict__ part2) {
    const int tid = threadIdx.x;
    const int ch  = blockIdx.x >> 5;        // 0..15
    const int pg  = blockIdx.x & 31;        // 0..31
    const int p   = pg * 256 + tid;
    const int cb  = ch * 32;

    float4 xr[32];
    const float4* xp = (const float4*)(X + (size_t)p * DD);
    #pragma unroll
    for (int i = 0; i < 32; ++i) xr[i] = xp[i];

    float bv = 3.4e38f;
    int   bi = 0;
    for (int cq = 0; cq < 8; ++cq) {
        const int c0 = cb + cq * 4;
        const float4* cr0 = (const float4*)(Ck + (size_t)(c0 + 0) * DD);
        const float4* cr1 = (const float4*)(Ck + (size_t)(c0 + 1) * DD);
        const float4* cr2 = (const float4*)(Ck + (size_t)(c0 + 2) * DD);
        const float4* cr3 = (const float4*)(Ck + (size_t)(c0 + 3) * DD);
        float a0 = 0.f, a1 = 0.f, a2 = 0.f, a3 = 0.f;
        #pragma unroll
        for (int i = 0; i < 32; ++i) {
            const float4 x4 = xr[i];
            const float4 v0 = cr0[i];
            const float4 v1 = cr1[i];
            const float4 v2 = cr2[i];
            const float4 v3 = cr3[i];
            a0 = fmaf(x4.x, v0.x, a0); a0 = fmaf(x4.y, v0.y, a0);
            a0 = fmaf(x4.z, v0.z, a0); a0 = fmaf(x4.w, v0.w, a0);
            a1 = fmaf(x4.x, v1.x, a1); a1 = fmaf(x4.y, v1.y, a1);
            a1 = fmaf(x4.z, v1.z, a1); a1 = fmaf(x4.w, v1.w, a1);
            a2 = fmaf(x4.x, v2.x, a2); a2 = fmaf(x4.y, v2.y, a2);
            a2 = fmaf(x4.z, v2.z, a2); a2 = fmaf(x4.w, v2.w, a2);
            a3 = fmaf(x4.x, v3.x, a3); a3 = fmaf(x4.y, v3.y, a3);
            a3 = fmaf(x4.z, v3.z, a3); a3 = fmaf(x4.w, v3.w, a3);
        }
        const float4 s2 = *(const float4*)(sumc2 + c0);
        float v;
        v = fmaf(-2.f, a0, s2.x); if (v < bv) { bv = v; bi = c0 + 0; }
        v = fmaf(-2.f, a1, s2.y); if (v < bv) { bv = v; bi = c0 + 1; }
        v = fmaf(-2.f, a2, s2.z); if (v < bv) { bv = v; bi = c0 + 2; }
        v = fmaf(-2.f, a3, s2.w); if (v < bv) { bv = v; bi = c0 + 3; }
    }
    // monotone float->uint; pack idx low so u64 min == (min v, then min idx)
    unsigned int b = __float_as_uint(bv);
    b = (b & 0x80000000u) ? ~b : (b | 0x80000000u);
    part2[(size_t)p * 16 + ch] = ((unsigned long long)b << 32) | (unsigned int)bi;
}

// ---------------- hist: min-combine chunks + LDS partial sums ----------------
// 256 blocks x 256 thr: g = b>>2 (128-point group), h = (b>>1)&1 (dim half),
// ch = b&1 (cluster half). LDS tile [256 c][64 d] = 64 KB. Fixed work per
// block regardless of skew (r9-proven, exact).
__global__ __launch_bounds__(256) void khist2(const float* __restrict__ X,
                                              const unsigned long long* __restrict__ part2,
                                              float* __restrict__ part,
                                              int* __restrict__ cntpart) {
    __shared__ float lds[256 * 64];   // 64 KB
    __shared__ int sidx[128];
    __shared__ int cnt[256];
    const int b = blockIdx.x;
    const int g = b >> 2, h = (b >> 1) & 1, ch = b & 1;
    const int t = threadIdx.x;
    const int lane = t & 63;
    const int w = t >> 6;

    {
        float4* lz = (float4*)lds;
        const float4 z = make_float4(0.f, 0.f, 0.f, 0.f);
        #pragma unroll
        for (int i = 0; i < 16; ++i) lz[t + 256 * i] = z;
    }
    cnt[t] = 0;
    if (t < 128) {
        const ulonglong2* pp = (const ulonglong2*)(part2 + (size_t)(g * 128 + t) * 16);
        unsigned long long m = ~0ull;
        #pragma unroll
        for (int i = 0; i < 8; ++i) {
            const ulonglong2 v = pp[i];
            m = (v.x < m) ? v.x : m;
            m = (v.y < m) ? v.y : m;
        }
        sidx[t] = (int)(m & 0xffffffffull);
    }
    __syncthreads();

    const int clo = ch * 256;
    if (h == 0 && t < 128) {
        const int cl = sidx[t] - clo;
        if ((unsigned)cl < 256u) atomicAdd(&cnt[cl], 1);
    }

    const float* Xh = X + (size_t)g * 128 * DD + h * 64 + lane;
    #pragma unroll 4
    for (int i = 0; i < 32; ++i) {
        const int p = w * 32 + i;
        const int cl = sidx[p] - clo;            // wave-uniform
        if ((unsigned)cl < 256u) {
            const float x = Xh[p * DD];          // 256B coalesced per wave
            atomicAdd(&lds[cl * 64 + lane], x);  // LDS ds_add_f32
        }
    }
    __syncthreads();

    // writeout 256x64 tile -> part[g][clo+cl][h*64 + d]  (4096 float4, 16/thread)
    const float4* ls = (const float4*)lds;
    float* pg_ = part + (size_t)g * (KC * DD);
    #pragma unroll
    for (int r = 0; r < 16; ++r) {
        const int j  = r * 256 + t;              // 0..4095
        const int cl = j >> 4;
        const int dq = j & 15;
        *(float4*)&pg_[(clo + cl) * DD + h * 64 + dq * 4] = ls[j];
    }
    if (h == 0) cntpart[g * KC + clo + t] = cnt[t];
}

// ---------------- reduce: out[c][:] = sum_g part[g][c][:], + nItems ----------------
// 512 blocks x 128 thr. Fixed ascending-g order (deterministic, exact).
__global__ __launch_bounds__(128) void kreduce2(const float* __restrict__ part,
                                                const int* __restrict__ cntpart,
                                                float* __restrict__ out) {
    const int c = blockIdx.x;
    const int d = threadIdx.x;
    const float* pc = part + (size_t)c * DD + d;
    float s = 0.f;
    #pragma unroll 8
    for (int g = 0; g < 64; ++g) s += pc[(size_t)g * (KC * DD)];
    out[c * DD + d] = s;

    if (d < 64) {
        int v = cntpart[d * KC + c];
        #pragma unroll
        for (int off = 32; off > 0; off >>= 1) v += __shfl_xor(v, off);
        if (d == 0) out[KC * DD + c] = (float)v;
    }
}

extern "C" void kernel_launch(void* const* d_in, const int* in_sizes, int n_in,
                              void* d_out, int out_size, void* d_ws, size_t ws_size,
                              hipStream_t stream) {
    const float* locF = (const float*)d_in[0];
    const float* Ck   = (const float*)d_in[1];
    float* out     = (float*)d_out;
    char*  ws      = (char*)d_ws;
    float* sumc2   = (float*)(ws);
    unsigned long long* part2 = (unsigned long long*)(ws + 4096);
    int*   cntpart = (int*)(ws + 1052672);
    float* part    = (float*)(ws + 1183744);

    hipLaunchKernelGGL(kprep,    dim3(2),   dim3(256), 0, stream, Ck, sumc2);
    hipLaunchKernelGGL(kassign2, dim3(512), dim3(256), 0, stream, locF, Ck, sumc2, part2);
    hipLaunchKernelGGL(khist2,   dim3(256), dim3(256), 0, stream, locF, part2, part, cntpart);
    hipLaunchKernelGGL(kreduce2, dim3(512), dim3(128), 0, stream, part, cntpart, out);
}